// Round 6
// baseline (863.866 us; speedup 1.0000x reference)
//
#include <hip/hip_runtime.h>
#include <hip/hip_fp16.h>

#define NN 200000
#define NE 6400000
#define F_IN 20
#define F_OUT 10
#define XPH 16              // xp row stride in halves: 32B, 2 rows per cache line
#define NEG_SLOPE 0.2f
#define BN_EPS 1e-5f

#define NPB 400             // nodes per bucket
#define NBUCK 500           // 500*400 == NN exactly
#define NBLK 625            // chunk blocks for count/scatter
#define CHUNK 10240         // 625*10240 == NE exactly
#define SZ (NBUCK * NBLK)   // 312500
#define SCANB 1024
#define G1 ((SZ + SCANB - 1) / SCANB)   // 306
#define HSB 240             // stats partial blocks
#define RT 1024             // creduce threads

// ---- workspace float/int offsets ----
#define OFF_C      41
#define OFF_LOOPAE 42
#define OFF_SCALE  64
#define OFF_SHIFT  84
#define OFF_PART   128                      // HSB*40 partials
#define OFF_PEW    (OFF_PART + HSB * 40)
#define OFF_AS     (OFF_PEW + HSB)
#define OFF_AD     (OFF_AS + NN)
#define OFF_XP     (OFF_AD + NN)            // fp16 table: 8*NN floats worth, 32B-aligned
#define OFF_SCN    (OFF_XP + 8 * NN)        // SZ+1 ints
#define OFF_BS     (OFF_SCN + SZ + 1)       // 1024 ints
#define OFF_M      (((OFF_BS + 1024) + 1) & ~1)  // SZ ints; REC overlays (dead after scan)
#define OFF_REC    OFF_M                    // 2*NE ints (8B records)

typedef unsigned long long u64;

// exact floor(d/400) for d < 2^30
__device__ __forceinline__ int bucket_of(int d) {
    return (int)(((u64)(unsigned)d * 687194768ull) >> 38);
}

// ---------------- column stats of h: per-block partials ----------------
__global__ void k_hstats(const float* __restrict__ h, float* __restrict__ part) {
    float s[F_IN], q[F_IN];
#pragma unroll
    for (int f = 0; f < F_IN; ++f) { s[f] = 0.f; q[f] = 0.f; }
    for (int i = blockIdx.x * blockDim.x + threadIdx.x; i < NN;
         i += gridDim.x * blockDim.x) {
        const float4* row = (const float4*)(h + (size_t)i * F_IN);
#pragma unroll
        for (int v = 0; v < 5; ++v) {
            float4 x = row[v];
            int f = v * 4;
            s[f+0] += x.x; q[f+0] += x.x * x.x;
            s[f+1] += x.y; q[f+1] += x.y * x.y;
            s[f+2] += x.z; q[f+2] += x.z * x.z;
            s[f+3] += x.w; q[f+3] += x.w * x.w;
        }
    }
#pragma unroll
    for (int f = 0; f < F_IN; ++f)
        for (int o = 32; o > 0; o >>= 1) {
            s[f] += __shfl_down(s[f], o);
            q[f] += __shfl_down(q[f], o);
        }
    __shared__ float red[4][40];
    int t = threadIdx.x, wave = t >> 6, lane = t & 63;
    if (lane == 0) {
#pragma unroll
        for (int f = 0; f < F_IN; ++f) { red[wave][f] = s[f]; red[wave][F_IN + f] = q[f]; }
    }
    __syncthreads();
    if (t < 40) part[blockIdx.x * 40 + t] = red[0][t] + red[1][t] + red[2][t] + red[3][t];
}

// ---------------- sum of edge_weight: per-block partials ----------------
__global__ void k_ewsum(const float* __restrict__ ew, float* __restrict__ pew) {
    float s = 0.f;
    const float4* e4 = (const float4*)ew;
    const int n4 = NE / 4;
    for (int i = blockIdx.x * blockDim.x + threadIdx.x; i < n4;
         i += gridDim.x * blockDim.x) {
        float4 x = e4[i];
        s += x.x + x.y + x.z + x.w;
    }
    for (int o = 32; o > 0; o >>= 1) s += __shfl_down(s, o);
    __shared__ float red[4];
    int t = threadIdx.x;
    if ((t & 63) == 0) red[t >> 6] = s;
    __syncthreads();
    if (t == 0) pew[blockIdx.x] = red[0] + red[1] + red[2] + red[3];
}

// ---------------- finalize scalar params ----------------
__global__ void k_params(const float* __restrict__ bn_w, const float* __restrict__ bn_b,
                         const float* __restrict__ W_edge, const float* __restrict__ att_edge,
                         const float* __restrict__ part, const float* __restrict__ pew,
                         float* __restrict__ ws) {
    __shared__ float col[40];
    __shared__ float ews;
    int t = threadIdx.x;
    if (t < 40) {
        float s = 0.f;
#pragma unroll 8
        for (int b = 0; b < HSB; ++b) s += part[b * 40 + t];
        col[t] = s;
    }
    if (t == 40) {
        float s = 0.f;
#pragma unroll 8
        for (int b = 0; b < HSB; ++b) s += pew[b];
        ews = s;
    }
    __syncthreads();
    if (t < F_IN) {
        float mu  = col[t] / (float)NN;
        float var = col[F_IN + t] / (float)NN - mu * mu;
        float sc  = bn_w[t] * rsqrtf(var + BN_EPS);
        ws[OFF_SCALE + t] = sc;
        ws[OFF_SHIFT + t] = bn_b[t] - mu * sc;
    }
    if (t == 63) {
        float c = 0.f;
#pragma unroll
        for (int k = 0; k < F_OUT; ++k) c += W_edge[k] * att_edge[k];
        ws[OFF_C] = c;
        ws[OFF_LOOPAE] = c * (ews / (float)NE);
    }
}

// ---------------- per-node: BN + projection + attention; xp stored fp16 ----------------
__global__ void k_node(const float* __restrict__ h, const float* __restrict__ W,
                       const float* __restrict__ att_src, const float* __restrict__ att_dst,
                       const float* __restrict__ ws_ro, __half* __restrict__ xph,
                       float* __restrict__ a_s, float* __restrict__ a_d) {
    __shared__ float sW[F_OUT * F_IN], sAs[F_OUT], sAd[F_OUT], sSc[F_IN], sSh[F_IN];
    int t = threadIdx.x;
    if (t < F_OUT * F_IN) sW[t] = W[t];
    if (t < F_OUT) { sAs[t] = att_src[t]; sAd[t] = att_dst[t]; }
    if (t >= 224 && t < 224 + F_IN) {
        sSc[t - 224] = ws_ro[OFF_SCALE + (t - 224)];
        sSh[t - 224] = ws_ro[OFF_SHIFT + (t - 224)];
    }
    __syncthreads();
    int i = blockIdx.x * blockDim.x + t;
    if (i >= NN) return;
    float xn[F_IN];
    const float4* row = (const float4*)(h + (size_t)i * F_IN);
#pragma unroll
    for (int v = 0; v < 5; ++v) {
        float4 x = row[v];
        int f = v * 4;
        xn[f+0] = x.x * sSc[f+0] + sSh[f+0];
        xn[f+1] = x.y * sSc[f+1] + sSh[f+1];
        xn[f+2] = x.z * sSc[f+2] + sSh[f+2];
        xn[f+3] = x.w * sSc[f+3] + sSh[f+3];
    }
    float acc[F_OUT];
    float as = 0.f, ad = 0.f;
#pragma unroll
    for (int k = 0; k < F_OUT; ++k) {
        float a = 0.f;
#pragma unroll
        for (int f = 0; f < F_IN; ++f) a += sW[k * F_IN + f] * xn[f];
        acc[k] = a;
        as += a * sAs[k];
        ad += a * sAd[k];
    }
    __half2 h01 = __floats2half2_rn(acc[0], acc[1]);
    __half2 h23 = __floats2half2_rn(acc[2], acc[3]);
    __half2 h45 = __floats2half2_rn(acc[4], acc[5]);
    __half2 h67 = __floats2half2_rn(acc[6], acc[7]);
    __half2 h89 = __floats2half2_rn(acc[8], acc[9]);
    unsigned* dst = (unsigned*)(xph + (size_t)i * XPH);
    uint4 U;
    U.x = *(unsigned*)&h01; U.y = *(unsigned*)&h23;
    U.z = *(unsigned*)&h45; U.w = *(unsigned*)&h67;
    *(uint4*)dst = U;
    dst[4] = *(unsigned*)&h89;
    a_s[i] = as;
    a_d[i] = ad;
}

// ---------------- pass A: per-(bucket, chunk) edge counts ----------------
__global__ void k_bcount(const int* __restrict__ ei, int* __restrict__ M) {
    __shared__ int hist[NBUCK];
    int t = threadIdx.x, blk = blockIdx.x;
    for (int i = t; i < NBUCK; i += 256) hist[i] = 0;
    __syncthreads();
    int base = blk * CHUNK;
#pragma unroll 2
    for (int j = t; j < CHUNK; j += 256) {
        int dst = __builtin_nontemporal_load(ei + NE + base + j);
        atomicAdd(&hist[bucket_of(dst)], 1);
    }
    __syncthreads();
    for (int i = t; i < NBUCK; i += 256) M[i * NBLK + blk] = hist[i];
}

// ---------------- scan ----------------
__global__ void k_scan1(const int* __restrict__ M, int* __restrict__ SCN,
                        int* __restrict__ BS) {
    __shared__ int tmp[SCANB];
    int t = threadIdx.x, g = blockIdx.x;
    int idx = g * SCANB + t;
    int v = (idx < SZ) ? M[idx] : 0;
    tmp[t] = v;
    __syncthreads();
    for (int off = 1; off < SCANB; off <<= 1) {
        int x = (t >= off) ? tmp[t - off] : 0;
        __syncthreads();
        tmp[t] += x;
        __syncthreads();
    }
    if (idx < SZ) SCN[idx] = tmp[t] - v;
    if (t == SCANB - 1) BS[g] = tmp[t];
}

__global__ void k_scan2(int* __restrict__ BS, int* __restrict__ SCN) {
    __shared__ int tmp[SCANB];
    int t = threadIdx.x;
    int v = (t < G1) ? BS[t] : 0;
    tmp[t] = v;
    __syncthreads();
    for (int off = 1; off < SCANB; off <<= 1) {
        int x = (t >= off) ? tmp[t - off] : 0;
        __syncthreads();
        tmp[t] += x;
        __syncthreads();
    }
    if (t < G1) BS[t] = tmp[t] - v;
    if (t == 0) SCN[SZ] = NE;
}

__global__ void k_scan3(int* __restrict__ SCN, const int* __restrict__ BS) {
    int idx = blockIdx.x * SCANB + threadIdx.x;
    if (idx < SZ) SCN[idx] += BS[blockIdx.x];
}

// ---------------- pass B: scatter records (nt stores keep L2 for tables) ----------------
__global__ void k_scatter(const int* __restrict__ ei, const float* __restrict__ ew,
                          const float* __restrict__ ws_ro,
                          const float* __restrict__ a_s, const float* __restrict__ a_d,
                          const int* __restrict__ SCN, u64* __restrict__ rec) {
    __shared__ int cur[NBUCK];
    int t = threadIdx.x, blk = blockIdx.x;
    for (int i = t; i < NBUCK; i += 256) cur[i] = SCN[i * NBLK + blk];
    __syncthreads();
    float c = ws_ro[OFF_C];
    int base = blk * CHUNK;
#pragma unroll 2
    for (int j = t; j < CHUNK; j += 256) {
        int e = base + j;
        int src = __builtin_nontemporal_load(ei + e);
        int dst = __builtin_nontemporal_load(ei + NE + e);
        float w  = __builtin_nontemporal_load(ew + e);
        float logit = a_s[src] + a_d[dst] + c * w;
        logit = logit > 0.f ? logit : NEG_SLOPE * logit;
        float ex = __expf(logit);
        int b = bucket_of(dst);
        int local = dst - b * NPB;            // < 400, fits 10 bits
        int pos = atomicAdd(&cur[b], 1);
        u64 rv = ((u64)__float_as_uint(ex) << 32) |
                 (u64)(((unsigned)src << 10) | (unsigned)local);
        __builtin_nontemporal_store(rv, rec + pos);
    }
}

// ---------------- pass C: per-bucket LDS accumulate + epilogue + MLP ----------------
__device__ __forceinline__ void accum_rec(unsigned lo, float ex, const uint4& A,
                                          unsigned B, float* __restrict__ acc) {
    float2 f0 = __half22float2(*(const __half2*)&A.x);
    float2 f1 = __half22float2(*(const __half2*)&A.y);
    float2 f2 = __half22float2(*(const __half2*)&A.z);
    float2 f3 = __half22float2(*(const __half2*)&A.w);
    float2 f4 = __half22float2(*(const __half2*)&B);
    float* q = acc + (lo & 1023u) * 11;
    atomicAdd(q + 0, ex);
    atomicAdd(q + 1, ex * f0.x); atomicAdd(q + 2, ex * f0.y);
    atomicAdd(q + 3, ex * f1.x); atomicAdd(q + 4, ex * f1.y);
    atomicAdd(q + 5, ex * f2.x); atomicAdd(q + 6, ex * f2.y);
    atomicAdd(q + 7, ex * f3.x); atomicAdd(q + 8, ex * f3.y);
    atomicAdd(q + 9, ex * f4.x); atomicAdd(q + 10, ex * f4.y);
}

__global__ void __launch_bounds__(RT, 8) k_creduce(
        const float* __restrict__ ws_ro, const int* __restrict__ SCN,
        const u64* __restrict__ rec, const __half* __restrict__ xph,
        const float* __restrict__ a_s, const float* __restrict__ a_d,
        const float* __restrict__ bias,
        const float* __restrict__ fc1w, const float* __restrict__ fc1b,
        const float* __restrict__ fc2w, const float* __restrict__ fc2b,
        const float* __restrict__ fc3w, const float* __restrict__ fc3b,
        float* __restrict__ out) {
    __shared__ float acc[NPB * 11];          // [local*11 + k]; k=0 den, 1..10 num
    __shared__ float s1[100], s2[100], s3[100], sb[F_OUT], sb1[F_OUT], sb2[F_OUT], sb3[F_OUT];
    int t = threadIdx.x, b = blockIdx.x;
    for (int i = t; i < NPB * 11; i += RT) acc[i] = 0.f;
    if (t < 100) { s1[t] = fc1w[t]; s2[t] = fc2w[t]; s3[t] = fc3w[t]; }
    if (t >= 128 && t < 128 + F_OUT) {
        int k = t - 128;
        sb[k] = bias[k]; sb1[k] = fc1b[k]; sb2[k] = fc2b[k]; sb3[k] = fc3b[k];
    }
    __syncthreads();
    int start = SCN[b * NBLK];
    int end   = SCN[(b + 1) * NBLK];
    int i = start + t;
    for (; i + 3 * RT < end; i += 4 * RT) {
        u64 r0 = __builtin_nontemporal_load(rec + i);
        u64 r1 = __builtin_nontemporal_load(rec + i + RT);
        u64 r2 = __builtin_nontemporal_load(rec + i + 2 * RT);
        u64 r3 = __builtin_nontemporal_load(rec + i + 3 * RT);
        unsigned l0 = (unsigned)r0, l1 = (unsigned)r1, l2 = (unsigned)r2, l3 = (unsigned)r3;
        const unsigned* p0 = (const unsigned*)(xph + (size_t)(l0 >> 10) * XPH);
        const unsigned* p1 = (const unsigned*)(xph + (size_t)(l1 >> 10) * XPH);
        const unsigned* p2 = (const unsigned*)(xph + (size_t)(l2 >> 10) * XPH);
        const unsigned* p3 = (const unsigned*)(xph + (size_t)(l3 >> 10) * XPH);
        uint4 A0 = *(const uint4*)p0; unsigned B0 = p0[4];
        uint4 A1 = *(const uint4*)p1; unsigned B1 = p1[4];
        uint4 A2 = *(const uint4*)p2; unsigned B2 = p2[4];
        uint4 A3 = *(const uint4*)p3; unsigned B3 = p3[4];
        accum_rec(l0, __uint_as_float((unsigned)(r0 >> 32)), A0, B0, acc);
        accum_rec(l1, __uint_as_float((unsigned)(r1 >> 32)), A1, B1, acc);
        accum_rec(l2, __uint_as_float((unsigned)(r2 >> 32)), A2, B2, acc);
        accum_rec(l3, __uint_as_float((unsigned)(r3 >> 32)), A3, B3, acc);
    }
    for (; i < end; i += RT) {
        u64 r0 = __builtin_nontemporal_load(rec + i);
        unsigned l0 = (unsigned)r0;
        const unsigned* p0 = (const unsigned*)(xph + (size_t)(l0 >> 10) * XPH);
        uint4 A0 = *(const uint4*)p0; unsigned B0 = p0[4];
        accum_rec(l0, __uint_as_float((unsigned)(r0 >> 32)), A0, B0, acc);
    }
    __syncthreads();
    if (t >= NPB) return;
    int node = b * NPB + t;                  // < NN always (500*400 == NN)
    float l = a_s[node] + a_d[node] + ws_ro[OFF_LOOPAE];
    l = l > 0.f ? l : NEG_SLOPE * l;
    float exs = __expf(l);
    float inv = 1.0f / (acc[t * 11] + exs);
    const unsigned* pn = (const unsigned*)(xph + (size_t)node * XPH);
    uint4 An = *(const uint4*)pn; unsigned Bn = pn[4];
    float xn[F_OUT];
    {
        float2 f0 = __half22float2(*(const __half2*)&An.x);
        float2 f1 = __half22float2(*(const __half2*)&An.y);
        float2 f2 = __half22float2(*(const __half2*)&An.z);
        float2 f3 = __half22float2(*(const __half2*)&An.w);
        float2 f4 = __half22float2(*(const __half2*)&Bn);
        xn[0]=f0.x; xn[1]=f0.y; xn[2]=f1.x; xn[3]=f1.y; xn[4]=f2.x;
        xn[5]=f2.y; xn[6]=f3.x; xn[7]=f3.y; xn[8]=f4.x; xn[9]=f4.y;
    }
    float o[F_OUT], y1[F_OUT], y2[F_OUT];
#pragma unroll
    for (int k = 0; k < F_OUT; ++k) {
        o[k] = (acc[t * 11 + 1 + k] + exs * xn[k]) * inv + sb[k];
        out[(size_t)node * F_OUT + k] = fmaxf(o[k], 0.f);   // embeddings
    }
#pragma unroll
    for (int k = 0; k < F_OUT; ++k) {
        float a = sb1[k];
#pragma unroll
        for (int jj = 0; jj < F_OUT; ++jj) a += s1[k * F_OUT + jj] * o[jj];
        y1[k] = fmaxf(a, 0.f);
    }
#pragma unroll
    for (int k = 0; k < F_OUT; ++k) {
        float a = sb2[k];
#pragma unroll
        for (int jj = 0; jj < F_OUT; ++jj) a += s2[k * F_OUT + jj] * y1[jj];
        y2[k] = fmaxf(a, 0.f);
    }
#pragma unroll
    for (int k = 0; k < F_OUT; ++k) {
        float a = sb3[k];
#pragma unroll
        for (int jj = 0; jj < F_OUT; ++jj) a += s3[k * F_OUT + jj] * y2[jj];
        out[(size_t)NN * F_OUT + (size_t)node * F_OUT + k] = a;   // y
    }
}

extern "C" void kernel_launch(void* const* d_in, const int* in_sizes, int n_in,
                              void* d_out, int out_size, void* d_ws, size_t ws_size,
                              hipStream_t stream) {
    const float* h        = (const float*)d_in[0];
    const int*   ei       = (const int*)  d_in[1];
    const float* ew       = (const float*)d_in[2];
    const float* bn_w     = (const float*)d_in[3];
    const float* bn_b     = (const float*)d_in[4];
    const float* W        = (const float*)d_in[5];
    const float* att_src  = (const float*)d_in[6];
    const float* att_dst  = (const float*)d_in[7];
    const float* att_edge = (const float*)d_in[8];
    const float* W_edge   = (const float*)d_in[9];
    const float* bias     = (const float*)d_in[10];
    const float* fc1w     = (const float*)d_in[11];
    const float* fc1b     = (const float*)d_in[12];
    const float* fc2w     = (const float*)d_in[13];
    const float* fc2b     = (const float*)d_in[14];
    const float* fc3w     = (const float*)d_in[15];
    const float* fc3b     = (const float*)d_in[16];
    float* ws  = (float*)d_ws;
    int*   wsi = (int*)d_ws;
    float* out = (float*)d_out;
    __half* xph = (__half*)(ws + OFF_XP);

    k_hstats<<<HSB, 256, 0, stream>>>(h, ws + OFF_PART);
    k_ewsum <<<HSB, 256, 0, stream>>>(ew, ws + OFF_PEW);
    k_params<<<1, 64, 0, stream>>>(bn_w, bn_b, W_edge, att_edge,
                                   ws + OFF_PART, ws + OFF_PEW, ws);
    k_node  <<<(NN + 255) / 256, 256, 0, stream>>>(h, W, att_src, att_dst, ws,
                                                   xph, ws + OFF_AS, ws + OFF_AD);
    k_bcount<<<NBLK, 256, 0, stream>>>(ei, wsi + OFF_M);
    k_scan1 <<<G1, SCANB, 0, stream>>>(wsi + OFF_M, wsi + OFF_SCN, wsi + OFF_BS);
    k_scan2 <<<1, SCANB, 0, stream>>>(wsi + OFF_BS, wsi + OFF_SCN);
    k_scan3 <<<G1, SCANB, 0, stream>>>(wsi + OFF_SCN, wsi + OFF_BS);
    k_scatter<<<NBLK, 256, 0, stream>>>(ei, ew, ws, ws + OFF_AS, ws + OFF_AD,
                                        wsi + OFF_SCN, (u64*)(wsi + OFF_REC));
    k_creduce<<<NBUCK, RT, 0, stream>>>(ws, wsi + OFF_SCN, (const u64*)(wsi + OFF_REC),
                                        xph, ws + OFF_AS, ws + OFF_AD,
                                        bias, fc1w, fc1b, fc2w, fc2b, fc3w, fc3b, out);
}

// Round 7
// 627.953 us; speedup vs baseline: 1.3757x; 1.3757x over previous
//
#include <hip/hip_runtime.h>
#include <hip/hip_fp16.h>

#define NN 200000
#define NE 6400000
#define F_IN 20
#define F_OUT 10
#define XPH 16              // xp row stride in halves: 32B, 2 rows per cache line
#define NEG_SLOPE 0.2f
#define BN_EPS 1e-5f

#define NPB 512             // nodes per bucket = dst >> 9 (power of 2)
#define NBUCK 391           // ceil(NN/512)
#define NBLK 625            // chunk blocks for count/scatter
#define CHUNK 10240         // 625*10240 == NE exactly
#define SZ (NBUCK * NBLK)   // 244375
#define SCANB 1024
#define G1 ((SZ + SCANB - 1) / SCANB)   // 239
#define HSB 240             // stats partial blocks
#define RT 512              // creduce threads (one per node in bucket)
#define MAXB 17664          // mean 16384 + 10 sigma; fits ushort

// ---- workspace float/int offsets ----
#define OFF_C      41
#define OFF_LOOPAE 42
#define OFF_SCALE  64
#define OFF_SHIFT  84
#define OFF_PART   128                      // HSB*40 partials
#define OFF_PEW    (OFF_PART + HSB * 40)
#define OFF_AS     (OFF_PEW + HSB)
#define OFF_AD     (OFF_AS + NN)
#define OFF_XP     (OFF_AD + NN)            // fp16 table: 8*NN floats worth, 32B-aligned
#define OFF_SCN    (OFF_XP + 8 * NN)        // SZ+1 ints
#define OFF_BS     (OFF_SCN + SZ + 1)       // 1024 ints
#define OFF_M      (((OFF_BS + 1024) + 1) & ~1)  // SZ ints; REC overlays (dead after scan)
#define OFF_REC    OFF_M                    // 2*NE ints (8B records)

typedef unsigned long long u64;

// ---------------- column stats of h: per-block partials ----------------
__global__ void k_hstats(const float* __restrict__ h, float* __restrict__ part) {
    float s[F_IN], q[F_IN];
#pragma unroll
    for (int f = 0; f < F_IN; ++f) { s[f] = 0.f; q[f] = 0.f; }
    for (int i = blockIdx.x * blockDim.x + threadIdx.x; i < NN;
         i += gridDim.x * blockDim.x) {
        const float4* row = (const float4*)(h + (size_t)i * F_IN);
#pragma unroll
        for (int v = 0; v < 5; ++v) {
            float4 x = row[v];
            int f = v * 4;
            s[f+0] += x.x; q[f+0] += x.x * x.x;
            s[f+1] += x.y; q[f+1] += x.y * x.y;
            s[f+2] += x.z; q[f+2] += x.z * x.z;
            s[f+3] += x.w; q[f+3] += x.w * x.w;
        }
    }
#pragma unroll
    for (int f = 0; f < F_IN; ++f)
        for (int o = 32; o > 0; o >>= 1) {
            s[f] += __shfl_down(s[f], o);
            q[f] += __shfl_down(q[f], o);
        }
    __shared__ float red[4][40];
    int t = threadIdx.x, wave = t >> 6, lane = t & 63;
    if (lane == 0) {
#pragma unroll
        for (int f = 0; f < F_IN; ++f) { red[wave][f] = s[f]; red[wave][F_IN + f] = q[f]; }
    }
    __syncthreads();
    if (t < 40) part[blockIdx.x * 40 + t] = red[0][t] + red[1][t] + red[2][t] + red[3][t];
}

// ---------------- sum of edge_weight: per-block partials ----------------
__global__ void k_ewsum(const float* __restrict__ ew, float* __restrict__ pew) {
    float s = 0.f;
    const float4* e4 = (const float4*)ew;
    const int n4 = NE / 4;
    for (int i = blockIdx.x * blockDim.x + threadIdx.x; i < n4;
         i += gridDim.x * blockDim.x) {
        float4 x = e4[i];
        s += x.x + x.y + x.z + x.w;
    }
    for (int o = 32; o > 0; o >>= 1) s += __shfl_down(s, o);
    __shared__ float red[4];
    int t = threadIdx.x;
    if ((t & 63) == 0) red[t >> 6] = s;
    __syncthreads();
    if (t == 0) pew[blockIdx.x] = red[0] + red[1] + red[2] + red[3];
}

// ---------------- finalize scalar params ----------------
__global__ void k_params(const float* __restrict__ bn_w, const float* __restrict__ bn_b,
                         const float* __restrict__ W_edge, const float* __restrict__ att_edge,
                         const float* __restrict__ part, const float* __restrict__ pew,
                         float* __restrict__ ws) {
    __shared__ float col[40];
    __shared__ float ews;
    int t = threadIdx.x;
    if (t < 40) {
        float s = 0.f;
#pragma unroll 8
        for (int b = 0; b < HSB; ++b) s += part[b * 40 + t];
        col[t] = s;
    }
    if (t == 40) {
        float s = 0.f;
#pragma unroll 8
        for (int b = 0; b < HSB; ++b) s += pew[b];
        ews = s;
    }
    __syncthreads();
    if (t < F_IN) {
        float mu  = col[t] / (float)NN;
        float var = col[F_IN + t] / (float)NN - mu * mu;
        float sc  = bn_w[t] * rsqrtf(var + BN_EPS);
        ws[OFF_SCALE + t] = sc;
        ws[OFF_SHIFT + t] = bn_b[t] - mu * sc;
    }
    if (t == 63) {
        float c = 0.f;
#pragma unroll
        for (int k = 0; k < F_OUT; ++k) c += W_edge[k] * att_edge[k];
        ws[OFF_C] = c;
        ws[OFF_LOOPAE] = c * (ews / (float)NE);
    }
}

// ---------------- per-node: BN + projection + attention; xp stored fp16 ----------------
__global__ void k_node(const float* __restrict__ h, const float* __restrict__ W,
                       const float* __restrict__ att_src, const float* __restrict__ att_dst,
                       const float* __restrict__ ws_ro, __half* __restrict__ xph,
                       float* __restrict__ a_s, float* __restrict__ a_d) {
    __shared__ float sW[F_OUT * F_IN], sAs[F_OUT], sAd[F_OUT], sSc[F_IN], sSh[F_IN];
    int t = threadIdx.x;
    if (t < F_OUT * F_IN) sW[t] = W[t];
    if (t < F_OUT) { sAs[t] = att_src[t]; sAd[t] = att_dst[t]; }
    if (t >= 224 && t < 224 + F_IN) {
        sSc[t - 224] = ws_ro[OFF_SCALE + (t - 224)];
        sSh[t - 224] = ws_ro[OFF_SHIFT + (t - 224)];
    }
    __syncthreads();
    int i = blockIdx.x * blockDim.x + t;
    if (i >= NN) return;
    float xn[F_IN];
    const float4* row = (const float4*)(h + (size_t)i * F_IN);
#pragma unroll
    for (int v = 0; v < 5; ++v) {
        float4 x = row[v];
        int f = v * 4;
        xn[f+0] = x.x * sSc[f+0] + sSh[f+0];
        xn[f+1] = x.y * sSc[f+1] + sSh[f+1];
        xn[f+2] = x.z * sSc[f+2] + sSh[f+2];
        xn[f+3] = x.w * sSc[f+3] + sSh[f+3];
    }
    float acc[F_OUT];
    float as = 0.f, ad = 0.f;
#pragma unroll
    for (int k = 0; k < F_OUT; ++k) {
        float a = 0.f;
#pragma unroll
        for (int f = 0; f < F_IN; ++f) a += sW[k * F_IN + f] * xn[f];
        acc[k] = a;
        as += a * sAs[k];
        ad += a * sAd[k];
    }
    __half2 h01 = __floats2half2_rn(acc[0], acc[1]);
    __half2 h23 = __floats2half2_rn(acc[2], acc[3]);
    __half2 h45 = __floats2half2_rn(acc[4], acc[5]);
    __half2 h67 = __floats2half2_rn(acc[6], acc[7]);
    __half2 h89 = __floats2half2_rn(acc[8], acc[9]);
    unsigned* dst = (unsigned*)(xph + (size_t)i * XPH);
    uint4 U;
    U.x = *(unsigned*)&h01; U.y = *(unsigned*)&h23;
    U.z = *(unsigned*)&h45; U.w = *(unsigned*)&h67;
    *(uint4*)dst = U;
    dst[4] = *(unsigned*)&h89;
    a_s[i] = as;
    a_d[i] = ad;
}

// ---------------- pass A: per-(bucket, chunk) edge counts ----------------
__global__ void k_bcount(const int* __restrict__ ei, int* __restrict__ M) {
    __shared__ int hist[NBUCK];
    int t = threadIdx.x, blk = blockIdx.x;
    for (int i = t; i < NBUCK; i += 256) hist[i] = 0;
    __syncthreads();
    int base = blk * CHUNK;
#pragma unroll 2
    for (int j = t; j < CHUNK; j += 256) {
        int dst = ei[NE + base + j];          // plain load: keep in L2 for k_scatter
        atomicAdd(&hist[dst >> 9], 1);
    }
    __syncthreads();
    for (int i = t; i < NBUCK; i += 256) M[i * NBLK + blk] = hist[i];
}

// ---------------- scan ----------------
__global__ void k_scan1(const int* __restrict__ M, int* __restrict__ SCN,
                        int* __restrict__ BS) {
    __shared__ int tmp[SCANB];
    int t = threadIdx.x, g = blockIdx.x;
    int idx = g * SCANB + t;
    int v = (idx < SZ) ? M[idx] : 0;
    tmp[t] = v;
    __syncthreads();
    for (int off = 1; off < SCANB; off <<= 1) {
        int x = (t >= off) ? tmp[t - off] : 0;
        __syncthreads();
        tmp[t] += x;
        __syncthreads();
    }
    if (idx < SZ) SCN[idx] = tmp[t] - v;
    if (t == SCANB - 1) BS[g] = tmp[t];
}

__global__ void k_scan2(int* __restrict__ BS, int* __restrict__ SCN) {
    __shared__ int tmp[SCANB];
    int t = threadIdx.x;
    int v = (t < G1) ? BS[t] : 0;
    tmp[t] = v;
    __syncthreads();
    for (int off = 1; off < SCANB; off <<= 1) {
        int x = (t >= off) ? tmp[t - off] : 0;
        __syncthreads();
        tmp[t] += x;
        __syncthreads();
    }
    if (t < G1) BS[t] = tmp[t] - v;
    if (t == 0) SCN[SZ] = NE;
}

__global__ void k_scan3(int* __restrict__ SCN, const int* __restrict__ BS) {
    int idx = blockIdx.x * SCANB + threadIdx.x;
    if (idx < SZ) SCN[idx] += BS[blockIdx.x];
}

// ---------------- pass B: scatter records into bucket order ----------------
__global__ void k_scatter(const int* __restrict__ ei, const float* __restrict__ ew,
                          const float* __restrict__ ws_ro,
                          const float* __restrict__ a_s, const float* __restrict__ a_d,
                          const int* __restrict__ SCN, u64* __restrict__ rec) {
    __shared__ int cur[NBUCK];
    int t = threadIdx.x, blk = blockIdx.x;
    for (int i = t; i < NBUCK; i += 256) cur[i] = SCN[i * NBLK + blk];
    __syncthreads();
    float c = ws_ro[OFF_C];
    int base = blk * CHUNK;
#pragma unroll 2
    for (int j = t; j < CHUNK; j += 256) {
        int e = base + j;
        int src = __builtin_nontemporal_load(ei + e);
        int dst = ei[NE + e];                 // second read of dst half — may hit L2
        float w  = __builtin_nontemporal_load(ew + e);
        float logit = a_s[src] + a_d[dst] + c * w;
        logit = logit > 0.f ? logit : NEG_SLOPE * logit;
        float ex = __expf(logit);
        int b = dst >> 9;
        int local = dst & (NPB - 1);          // 9 bits
        int pos = atomicAdd(&cur[b], 1);
        u64 rv = ((u64)__float_as_uint(ex) << 32) |
                 (u64)(((unsigned)src << 9) | (unsigned)local);
        __builtin_nontemporal_store(rv, rec + pos);
    }
}

// ---------------- pass C: in-bucket counting sort + register accumulate + MLP ----------------
__global__ void __launch_bounds__(RT, 8) k_creduce(
        const float* __restrict__ ws_ro, const int* __restrict__ SCN,
        const u64* __restrict__ rec, const __half* __restrict__ xph,
        const float* __restrict__ a_s, const float* __restrict__ a_d,
        const float* __restrict__ bias,
        const float* __restrict__ fc1w, const float* __restrict__ fc1b,
        const float* __restrict__ fc2w, const float* __restrict__ fc2b,
        const float* __restrict__ fc3w, const float* __restrict__ fc3b,
        float* __restrict__ out) {
    __shared__ unsigned short sIdx[MAXB];
    __shared__ int sHist[RT];                // hist -> scan (in place) -> cursor
    __shared__ float s1[100], s2[100], s3[100], sb[F_OUT], sb1[F_OUT], sb2[F_OUT], sb3[F_OUT];
    int t = threadIdx.x, b = blockIdx.x;
    sHist[t] = 0;
    if (t < 100) { s1[t] = fc1w[t]; s2[t] = fc2w[t]; s3[t] = fc3w[t]; }
    if (t >= 128 && t < 128 + F_OUT) {
        int k = t - 128;
        sb[k] = bias[k]; sb1[k] = fc1b[k]; sb2[k] = fc2b[k]; sb3[k] = fc3b[k];
    }
    __syncthreads();
    int start = SCN[b * NBLK];
    int cnt = SCN[(b + 1) * NBLK] - start;
    if (cnt > MAXB) cnt = MAXB;              // 10-sigma safety clamp
    const unsigned* recx = (const unsigned*)rec;
    // phase 1: histogram of local node (1 int LDS atomic per record)
    for (int i = t; i < cnt; i += RT)
        atomicAdd(&sHist[recx[2 * (size_t)(start + i)] & (NPB - 1u)], 1);
    __syncthreads();
    // phase 2: in-place Hillis-Steele exclusive scan over RT bins
    int deg = sHist[t];
    for (int off = 1; off < RT; off <<= 1) {
        int x = (t >= off) ? sHist[t - off] : 0;
        __syncthreads();
        sHist[t] += x;
        __syncthreads();
    }
    int myStart = sHist[t] - deg;
    __syncthreads();
    sHist[t] = myStart;                      // reuse as cursor
    __syncthreads();
    // phase 3: scatter record indices into node-sorted order (1 int LDS atomic per record)
    for (int i = t; i < cnt; i += RT) {
        unsigned lo = recx[2 * (size_t)(start + i)];
        int p = atomicAdd(&sHist[lo & (NPB - 1u)], 1);
        if (p < MAXB) sIdx[p] = (unsigned short)i;
    }
    __syncthreads();
    // phase 4: thread t exclusively owns node t — register accumulation, no atomics
    float den = 0.f;
    float num[F_OUT];
#pragma unroll
    for (int k = 0; k < F_OUT; ++k) num[k] = 0.f;
    int e0 = myStart + deg;
    int j = myStart;
    for (; j + 1 < e0; j += 2) {
        int i1 = start + sIdx[j];
        int i2 = start + sIdx[j + 1];
        u64 r1 = rec[i1];
        u64 r2 = rec[i2];
        float ex1 = __uint_as_float((unsigned)(r1 >> 32));
        float ex2 = __uint_as_float((unsigned)(r2 >> 32));
        const unsigned* p1 = (const unsigned*)(xph + (size_t)((unsigned)r1 >> 9) * XPH);
        const unsigned* p2 = (const unsigned*)(xph + (size_t)((unsigned)r2 >> 9) * XPH);
        uint4 A1 = *(const uint4*)p1; unsigned B1 = p1[4];
        uint4 A2 = *(const uint4*)p2; unsigned B2 = p2[4];
        float2 f0 = __half22float2(*(const __half2*)&A1.x);
        float2 f1 = __half22float2(*(const __half2*)&A1.y);
        float2 f2 = __half22float2(*(const __half2*)&A1.z);
        float2 f3 = __half22float2(*(const __half2*)&A1.w);
        float2 f4 = __half22float2(*(const __half2*)&B1);
        float2 g0 = __half22float2(*(const __half2*)&A2.x);
        float2 g1 = __half22float2(*(const __half2*)&A2.y);
        float2 g2 = __half22float2(*(const __half2*)&A2.z);
        float2 g3 = __half22float2(*(const __half2*)&A2.w);
        float2 g4 = __half22float2(*(const __half2*)&B2);
        den += ex1 + ex2;
        num[0] += ex1 * f0.x + ex2 * g0.x;
        num[1] += ex1 * f0.y + ex2 * g0.y;
        num[2] += ex1 * f1.x + ex2 * g1.x;
        num[3] += ex1 * f1.y + ex2 * g1.y;
        num[4] += ex1 * f2.x + ex2 * g2.x;
        num[5] += ex1 * f2.y + ex2 * g2.y;
        num[6] += ex1 * f3.x + ex2 * g3.x;
        num[7] += ex1 * f3.y + ex2 * g3.y;
        num[8] += ex1 * f4.x + ex2 * g4.x;
        num[9] += ex1 * f4.y + ex2 * g4.y;
    }
    if (j < e0) {
        int i1 = start + sIdx[j];
        u64 r1 = rec[i1];
        float ex1 = __uint_as_float((unsigned)(r1 >> 32));
        const unsigned* p1 = (const unsigned*)(xph + (size_t)((unsigned)r1 >> 9) * XPH);
        uint4 A1 = *(const uint4*)p1; unsigned B1 = p1[4];
        float2 f0 = __half22float2(*(const __half2*)&A1.x);
        float2 f1 = __half22float2(*(const __half2*)&A1.y);
        float2 f2 = __half22float2(*(const __half2*)&A1.z);
        float2 f3 = __half22float2(*(const __half2*)&A1.w);
        float2 f4 = __half22float2(*(const __half2*)&B1);
        den += ex1;
        num[0] += ex1 * f0.x; num[1] += ex1 * f0.y;
        num[2] += ex1 * f1.x; num[3] += ex1 * f1.y;
        num[4] += ex1 * f2.x; num[5] += ex1 * f2.y;
        num[6] += ex1 * f3.x; num[7] += ex1 * f3.y;
        num[8] += ex1 * f4.x; num[9] += ex1 * f4.y;
    }
    int node = b * NPB + t;
    if (node >= NN) return;                  // no barriers after this point
    float l = a_s[node] + a_d[node] + ws_ro[OFF_LOOPAE];
    l = l > 0.f ? l : NEG_SLOPE * l;
    float exs = __expf(l);
    float inv = 1.0f / (den + exs);
    const unsigned* pn = (const unsigned*)(xph + (size_t)node * XPH);
    uint4 An = *(const uint4*)pn; unsigned Bn = pn[4];
    float xn[F_OUT];
    {
        float2 f0 = __half22float2(*(const __half2*)&An.x);
        float2 f1 = __half22float2(*(const __half2*)&An.y);
        float2 f2 = __half22float2(*(const __half2*)&An.z);
        float2 f3 = __half22float2(*(const __half2*)&An.w);
        float2 f4 = __half22float2(*(const __half2*)&Bn);
        xn[0]=f0.x; xn[1]=f0.y; xn[2]=f1.x; xn[3]=f1.y; xn[4]=f2.x;
        xn[5]=f2.y; xn[6]=f3.x; xn[7]=f3.y; xn[8]=f4.x; xn[9]=f4.y;
    }
    float o[F_OUT], y1[F_OUT], y2[F_OUT];
#pragma unroll
    for (int k = 0; k < F_OUT; ++k) {
        o[k] = (num[k] + exs * xn[k]) * inv + sb[k];
        out[(size_t)node * F_OUT + k] = fmaxf(o[k], 0.f);   // embeddings
    }
#pragma unroll
    for (int k = 0; k < F_OUT; ++k) {
        float a = sb1[k];
#pragma unroll
        for (int jj = 0; jj < F_OUT; ++jj) a += s1[k * F_OUT + jj] * o[jj];
        y1[k] = fmaxf(a, 0.f);
    }
#pragma unroll
    for (int k = 0; k < F_OUT; ++k) {
        float a = sb2[k];
#pragma unroll
        for (int jj = 0; jj < F_OUT; ++jj) a += s2[k * F_OUT + jj] * y1[jj];
        y2[k] = fmaxf(a, 0.f);
    }
#pragma unroll
    for (int k = 0; k < F_OUT; ++k) {
        float a = sb3[k];
#pragma unroll
        for (int jj = 0; jj < F_OUT; ++jj) a += s3[k * F_OUT + jj] * y2[jj];
        out[(size_t)NN * F_OUT + (size_t)node * F_OUT + k] = a;   // y
    }
}

extern "C" void kernel_launch(void* const* d_in, const int* in_sizes, int n_in,
                              void* d_out, int out_size, void* d_ws, size_t ws_size,
                              hipStream_t stream) {
    const float* h        = (const float*)d_in[0];
    const int*   ei       = (const int*)  d_in[1];
    const float* ew       = (const float*)d_in[2];
    const float* bn_w     = (const float*)d_in[3];
    const float* bn_b     = (const float*)d_in[4];
    const float* W        = (const float*)d_in[5];
    const float* att_src  = (const float*)d_in[6];
    const float* att_dst  = (const float*)d_in[7];
    const float* att_edge = (const float*)d_in[8];
    const float* W_edge   = (const float*)d_in[9];
    const float* bias     = (const float*)d_in[10];
    const float* fc1w     = (const float*)d_in[11];
    const float* fc1b     = (const float*)d_in[12];
    const float* fc2w     = (const float*)d_in[13];
    const float* fc2b     = (const float*)d_in[14];
    const float* fc3w     = (const float*)d_in[15];
    const float* fc3b     = (const float*)d_in[16];
    float* ws  = (float*)d_ws;
    int*   wsi = (int*)d_ws;
    float* out = (float*)d_out;
    __half* xph = (__half*)(ws + OFF_XP);

    k_hstats<<<HSB, 256, 0, stream>>>(h, ws + OFF_PART);
    k_ewsum <<<HSB, 256, 0, stream>>>(ew, ws + OFF_PEW);
    k_params<<<1, 64, 0, stream>>>(bn_w, bn_b, W_edge, att_edge,
                                   ws + OFF_PART, ws + OFF_PEW, ws);
    k_node  <<<(NN + 255) / 256, 256, 0, stream>>>(h, W, att_src, att_dst, ws,
                                                   xph, ws + OFF_AS, ws + OFF_AD);
    k_bcount<<<NBLK, 256, 0, stream>>>(ei, wsi + OFF_M);
    k_scan1 <<<G1, SCANB, 0, stream>>>(wsi + OFF_M, wsi + OFF_SCN, wsi + OFF_BS);
    k_scan2 <<<1, SCANB, 0, stream>>>(wsi + OFF_BS, wsi + OFF_SCN);
    k_scan3 <<<G1, SCANB, 0, stream>>>(wsi + OFF_SCN, wsi + OFF_BS);
    k_scatter<<<NBLK, 256, 0, stream>>>(ei, ew, ws, ws + OFF_AS, ws + OFF_AD,
                                        wsi + OFF_SCN, (u64*)(wsi + OFF_REC));
    k_creduce<<<NBUCK, RT, 0, stream>>>(ws, wsi + OFF_SCN, (const u64*)(wsi + OFF_REC),
                                        xph, ws + OFF_AS, ws + OFF_AD,
                                        bias, fc1w, fc1b, fc2w, fc2b, fc3w, fc3b, out);
}

// Round 8
// 532.051 us; speedup vs baseline: 1.6237x; 1.1802x over previous
//
#include <hip/hip_runtime.h>
#include <hip/hip_fp16.h>

#define NN 200000
#define NE 6400000
#define F_IN 20
#define F_OUT 10
#define XPH 16              // xp row stride in halves: 32B, 2 rows per cache line
#define NEG_SLOPE 0.2f
#define BN_EPS 1e-5f

#define NPB 512             // nodes per bucket = dst >> 9 (power of 2)
#define NBUCK 391           // ceil(NN/512)
#define NBLK 625            // chunk blocks for count/scatter
#define CHUNK 10240         // 625*10240 == NE exactly
#define SB 512              // scatter/bcount block size
#define SZ (NBUCK * NBLK)   // 244375
#define SCANB 1024
#define G1 ((SZ + SCANB - 1) / SCANB)   // 239
#define HSB 240             // stats partial blocks
#define RT 512              // creduce threads (one per node in bucket)
#define MAXB 17664          // mean 16384 + 10 sigma; fits ushort

// ---- workspace float/int offsets ----
#define OFF_C      41
#define OFF_LOOPAE 42
#define OFF_SCALE  64
#define OFF_SHIFT  84
#define OFF_PART   128                      // HSB*40 partials
#define OFF_PEW    (OFF_PART + HSB * 40)
#define OFF_AS     (OFF_PEW + HSB)
#define OFF_AD     (OFF_AS + NN)
#define OFF_XP     (OFF_AD + NN)            // fp16 table: 8*NN floats worth, 32B-aligned
#define OFF_SCN    (OFF_XP + 8 * NN)        // SZ+1 ints
#define OFF_BS     (OFF_SCN + SZ + 1)       // 1024 ints
#define OFF_M      (((OFF_BS + 1024) + 1) & ~1)  // SZ ints; REC overlays (dead after scan)
#define OFF_REC    OFF_M                    // 2*NE ints (8B records)

typedef unsigned long long u64;

// ---------------- column stats of h: per-block partials ----------------
__global__ void k_hstats(const float* __restrict__ h, float* __restrict__ part) {
    float s[F_IN], q[F_IN];
#pragma unroll
    for (int f = 0; f < F_IN; ++f) { s[f] = 0.f; q[f] = 0.f; }
    for (int i = blockIdx.x * blockDim.x + threadIdx.x; i < NN;
         i += gridDim.x * blockDim.x) {
        const float4* row = (const float4*)(h + (size_t)i * F_IN);
#pragma unroll
        for (int v = 0; v < 5; ++v) {
            float4 x = row[v];
            int f = v * 4;
            s[f+0] += x.x; q[f+0] += x.x * x.x;
            s[f+1] += x.y; q[f+1] += x.y * x.y;
            s[f+2] += x.z; q[f+2] += x.z * x.z;
            s[f+3] += x.w; q[f+3] += x.w * x.w;
        }
    }
#pragma unroll
    for (int f = 0; f < F_IN; ++f)
        for (int o = 32; o > 0; o >>= 1) {
            s[f] += __shfl_down(s[f], o);
            q[f] += __shfl_down(q[f], o);
        }
    __shared__ float red[4][40];
    int t = threadIdx.x, wave = t >> 6, lane = t & 63;
    if (lane == 0) {
#pragma unroll
        for (int f = 0; f < F_IN; ++f) { red[wave][f] = s[f]; red[wave][F_IN + f] = q[f]; }
    }
    __syncthreads();
    if (t < 40) part[blockIdx.x * 40 + t] = red[0][t] + red[1][t] + red[2][t] + red[3][t];
}

// ---------------- sum of edge_weight: per-block partials ----------------
__global__ void k_ewsum(const float* __restrict__ ew, float* __restrict__ pew) {
    float s = 0.f;
    const float4* e4 = (const float4*)ew;
    const int n4 = NE / 4;
    for (int i = blockIdx.x * blockDim.x + threadIdx.x; i < n4;
         i += gridDim.x * blockDim.x) {
        float4 x = e4[i];
        s += x.x + x.y + x.z + x.w;
    }
    for (int o = 32; o > 0; o >>= 1) s += __shfl_down(s, o);
    __shared__ float red[4];
    int t = threadIdx.x;
    if ((t & 63) == 0) red[t >> 6] = s;
    __syncthreads();
    if (t == 0) pew[blockIdx.x] = red[0] + red[1] + red[2] + red[3];
}

// ---------------- finalize scalar params ----------------
__global__ void k_params(const float* __restrict__ bn_w, const float* __restrict__ bn_b,
                         const float* __restrict__ W_edge, const float* __restrict__ att_edge,
                         const float* __restrict__ part, const float* __restrict__ pew,
                         float* __restrict__ ws) {
    __shared__ float col[40];
    __shared__ float ews;
    int t = threadIdx.x;
    if (t < 40) {
        float s = 0.f;
#pragma unroll 8
        for (int b = 0; b < HSB; ++b) s += part[b * 40 + t];
        col[t] = s;
    }
    if (t == 40) {
        float s = 0.f;
#pragma unroll 8
        for (int b = 0; b < HSB; ++b) s += pew[b];
        ews = s;
    }
    __syncthreads();
    if (t < F_IN) {
        float mu  = col[t] / (float)NN;
        float var = col[F_IN + t] / (float)NN - mu * mu;
        float sc  = bn_w[t] * rsqrtf(var + BN_EPS);
        ws[OFF_SCALE + t] = sc;
        ws[OFF_SHIFT + t] = bn_b[t] - mu * sc;
    }
    if (t == 63) {
        float c = 0.f;
#pragma unroll
        for (int k = 0; k < F_OUT; ++k) c += W_edge[k] * att_edge[k];
        ws[OFF_C] = c;
        ws[OFF_LOOPAE] = c * (ews / (float)NE);
    }
}

// ---------------- per-node: BN + projection + attention; xp stored fp16 ----------------
__global__ void k_node(const float* __restrict__ h, const float* __restrict__ W,
                       const float* __restrict__ att_src, const float* __restrict__ att_dst,
                       const float* __restrict__ ws_ro, __half* __restrict__ xph,
                       float* __restrict__ a_s, float* __restrict__ a_d) {
    __shared__ float sW[F_OUT * F_IN], sAs[F_OUT], sAd[F_OUT], sSc[F_IN], sSh[F_IN];
    int t = threadIdx.x;
    if (t < F_OUT * F_IN) sW[t] = W[t];
    if (t < F_OUT) { sAs[t] = att_src[t]; sAd[t] = att_dst[t]; }
    if (t >= 224 && t < 224 + F_IN) {
        sSc[t - 224] = ws_ro[OFF_SCALE + (t - 224)];
        sSh[t - 224] = ws_ro[OFF_SHIFT + (t - 224)];
    }
    __syncthreads();
    int i = blockIdx.x * blockDim.x + t;
    if (i >= NN) return;
    float xn[F_IN];
    const float4* row = (const float4*)(h + (size_t)i * F_IN);
#pragma unroll
    for (int v = 0; v < 5; ++v) {
        float4 x = row[v];
        int f = v * 4;
        xn[f+0] = x.x * sSc[f+0] + sSh[f+0];
        xn[f+1] = x.y * sSc[f+1] + sSh[f+1];
        xn[f+2] = x.z * sSc[f+2] + sSh[f+2];
        xn[f+3] = x.w * sSc[f+3] + sSh[f+3];
    }
    float acc[F_OUT];
    float as = 0.f, ad = 0.f;
#pragma unroll
    for (int k = 0; k < F_OUT; ++k) {
        float a = 0.f;
#pragma unroll
        for (int f = 0; f < F_IN; ++f) a += sW[k * F_IN + f] * xn[f];
        acc[k] = a;
        as += a * sAs[k];
        ad += a * sAd[k];
    }
    __half2 h01 = __floats2half2_rn(acc[0], acc[1]);
    __half2 h23 = __floats2half2_rn(acc[2], acc[3]);
    __half2 h45 = __floats2half2_rn(acc[4], acc[5]);
    __half2 h67 = __floats2half2_rn(acc[6], acc[7]);
    __half2 h89 = __floats2half2_rn(acc[8], acc[9]);
    unsigned* dst = (unsigned*)(xph + (size_t)i * XPH);
    uint4 U;
    U.x = *(unsigned*)&h01; U.y = *(unsigned*)&h23;
    U.z = *(unsigned*)&h45; U.w = *(unsigned*)&h67;
    *(uint4*)dst = U;
    dst[4] = *(unsigned*)&h89;
    a_s[i] = as;
    a_d[i] = ad;
}

// ---------------- pass A: per-(bucket, chunk) edge counts ----------------
__global__ void k_bcount(const int* __restrict__ ei, int* __restrict__ M) {
    __shared__ int hist[NBUCK];
    int t = threadIdx.x, blk = blockIdx.x;
    for (int i = t; i < NBUCK; i += SB) hist[i] = 0;
    __syncthreads();
    int base = blk * CHUNK;
#pragma unroll 2
    for (int j = t; j < CHUNK; j += SB) {
        int dst = ei[NE + base + j];          // plain load: keep in L2 for k_scatter
        atomicAdd(&hist[dst >> 9], 1);
    }
    __syncthreads();
    for (int i = t; i < NBUCK; i += SB) M[i * NBLK + blk] = hist[i];
}

// ---------------- scan ----------------
__global__ void k_scan1(const int* __restrict__ M, int* __restrict__ SCN,
                        int* __restrict__ BS) {
    __shared__ int tmp[SCANB];
    int t = threadIdx.x, g = blockIdx.x;
    int idx = g * SCANB + t;
    int v = (idx < SZ) ? M[idx] : 0;
    tmp[t] = v;
    __syncthreads();
    for (int off = 1; off < SCANB; off <<= 1) {
        int x = (t >= off) ? tmp[t - off] : 0;
        __syncthreads();
        tmp[t] += x;
        __syncthreads();
    }
    if (idx < SZ) SCN[idx] = tmp[t] - v;
    if (t == SCANB - 1) BS[g] = tmp[t];
}

__global__ void k_scan2(int* __restrict__ BS, int* __restrict__ SCN) {
    __shared__ int tmp[SCANB];
    int t = threadIdx.x;
    int v = (t < G1) ? BS[t] : 0;
    tmp[t] = v;
    __syncthreads();
    for (int off = 1; off < SCANB; off <<= 1) {
        int x = (t >= off) ? tmp[t - off] : 0;
        __syncthreads();
        tmp[t] += x;
        __syncthreads();
    }
    if (t < G1) BS[t] = tmp[t] - v;
    if (t == 0) SCN[SZ] = NE;
}

__global__ void k_scan3(int* __restrict__ SCN, const int* __restrict__ BS) {
    int idx = blockIdx.x * SCANB + threadIdx.x;
    if (idx < SZ) SCN[idx] += BS[blockIdx.x];
}

// ---------------- pass B: scatter records into bucket order ----------------
// Plain stores: scattered 8B records merge in L2 into mostly-full lines (runs
// of ~26 records per (bucket,chunk)); nt stores write-through at 32B granules
// and cost 4x write amplification (measured r7: 204.7 MB for 51.2 MB).
__global__ void k_scatter(const int* __restrict__ ei, const float* __restrict__ ew,
                          const float* __restrict__ ws_ro,
                          const float* __restrict__ a_s, const float* __restrict__ a_d,
                          const int* __restrict__ SCN, u64* __restrict__ rec) {
    __shared__ int cur[NBUCK];
    int t = threadIdx.x, blk = blockIdx.x;
    for (int i = t; i < NBUCK; i += SB) cur[i] = SCN[i * NBLK + blk];
    __syncthreads();
    float c = ws_ro[OFF_C];
    int base = blk * CHUNK;
#pragma unroll 2
    for (int j = t; j < CHUNK; j += SB) {
        int e = base + j;
        int src = __builtin_nontemporal_load(ei + e);
        int dst = ei[NE + e];                 // second read of dst half — L2 hit
        float w  = __builtin_nontemporal_load(ew + e);
        float logit = a_s[src] + a_d[dst] + c * w;
        logit = logit > 0.f ? logit : NEG_SLOPE * logit;
        float ex = __expf(logit);
        int b = dst >> 9;
        int local = dst & (NPB - 1);          // 9 bits
        int pos = atomicAdd(&cur[b], 1);
        rec[pos] = ((u64)__float_as_uint(ex) << 32) |
                   (u64)(((unsigned)src << 9) | (unsigned)local);
    }
}

// ---------------- pass C: in-bucket counting sort + register accumulate + MLP ----------------
__device__ __forceinline__ void gath(const __half* __restrict__ xph, u64 r,
                                     float& ex, float2& f0, float2& f1,
                                     float2& f2, float2& f3, float2& f4) {
    ex = __uint_as_float((unsigned)(r >> 32));
    const unsigned* p = (const unsigned*)(xph + (size_t)((unsigned)r >> 9) * XPH);
    uint4 A = *(const uint4*)p; unsigned B = p[4];
    f0 = __half22float2(*(const __half2*)&A.x);
    f1 = __half22float2(*(const __half2*)&A.y);
    f2 = __half22float2(*(const __half2*)&A.z);
    f3 = __half22float2(*(const __half2*)&A.w);
    f4 = __half22float2(*(const __half2*)&B);
}

__global__ void __launch_bounds__(RT, 8) k_creduce(
        const float* __restrict__ ws_ro, const int* __restrict__ SCN,
        const u64* __restrict__ rec, const __half* __restrict__ xph,
        const float* __restrict__ a_s, const float* __restrict__ a_d,
        const float* __restrict__ bias,
        const float* __restrict__ fc1w, const float* __restrict__ fc1b,
        const float* __restrict__ fc2w, const float* __restrict__ fc2b,
        const float* __restrict__ fc3w, const float* __restrict__ fc3b,
        float* __restrict__ out) {
    __shared__ unsigned short sIdx[MAXB];
    __shared__ int sHist[RT];                // hist -> scan (in place) -> cursor
    __shared__ float s1[100], s2[100], s3[100], sb[F_OUT], sb1[F_OUT], sb2[F_OUT], sb3[F_OUT];
    int t = threadIdx.x, b = blockIdx.x;
    sHist[t] = 0;
    if (t < 100) { s1[t] = fc1w[t]; s2[t] = fc2w[t]; s3[t] = fc3w[t]; }
    if (t >= 128 && t < 128 + F_OUT) {
        int k = t - 128;
        sb[k] = bias[k]; sb1[k] = fc1b[k]; sb2[k] = fc2b[k]; sb3[k] = fc3b[k];
    }
    __syncthreads();
    int start = SCN[b * NBLK];
    int cnt = SCN[(b + 1) * NBLK] - start;
    if (cnt > MAXB) cnt = MAXB;              // 10-sigma safety clamp
    const unsigned* recx = (const unsigned*)rec;
    // phase 1: histogram of local node (1 int LDS atomic per record)
    for (int i = t; i < cnt; i += RT)
        atomicAdd(&sHist[recx[2 * (size_t)(start + i)] & (NPB - 1u)], 1);
    __syncthreads();
    // phase 2: in-place Hillis-Steele exclusive scan over RT bins
    int deg = sHist[t];
    for (int off = 1; off < RT; off <<= 1) {
        int x = (t >= off) ? sHist[t - off] : 0;
        __syncthreads();
        sHist[t] += x;
        __syncthreads();
    }
    int myStart = sHist[t] - deg;
    __syncthreads();
    sHist[t] = myStart;                      // reuse as cursor
    __syncthreads();
    // phase 3: scatter record indices into node-sorted order (1 int LDS atomic per record)
    for (int i = t; i < cnt; i += RT) {
        unsigned lo = recx[2 * (size_t)(start + i)];
        int p = atomicAdd(&sHist[lo & (NPB - 1u)], 1);
        if (p < MAXB) sIdx[p] = (unsigned short)i;
    }
    __syncthreads();
    // phase 4: thread t exclusively owns node t — register accumulation, no atomics
    float den = 0.f;
    float num[F_OUT];
#pragma unroll
    for (int k = 0; k < F_OUT; ++k) num[k] = 0.f;
    int e0 = myStart + deg;
    int j = myStart;
    for (; j + 3 < e0; j += 4) {
        u64 r1 = rec[start + sIdx[j]];
        u64 r2 = rec[start + sIdx[j + 1]];
        u64 r3 = rec[start + sIdx[j + 2]];
        u64 r4 = rec[start + sIdx[j + 3]];
        float e1, e2, e3, e4;
        float2 f0, f1, f2, f3, f4, g0, g1, g2, g3, g4;
        float2 h0, h1, h2, h3, h4, k0, k1, k2, k3, k4;
        gath(xph, r1, e1, f0, f1, f2, f3, f4);
        gath(xph, r2, e2, g0, g1, g2, g3, g4);
        gath(xph, r3, e3, h0, h1, h2, h3, h4);
        gath(xph, r4, e4, k0, k1, k2, k3, k4);
        den += (e1 + e2) + (e3 + e4);
        num[0] += e1 * f0.x + e2 * g0.x + e3 * h0.x + e4 * k0.x;
        num[1] += e1 * f0.y + e2 * g0.y + e3 * h0.y + e4 * k0.y;
        num[2] += e1 * f1.x + e2 * g1.x + e3 * h1.x + e4 * k1.x;
        num[3] += e1 * f1.y + e2 * g1.y + e3 * h1.y + e4 * k1.y;
        num[4] += e1 * f2.x + e2 * g2.x + e3 * h2.x + e4 * k2.x;
        num[5] += e1 * f2.y + e2 * g2.y + e3 * h2.y + e4 * k2.y;
        num[6] += e1 * f3.x + e2 * g3.x + e3 * h3.x + e4 * k3.x;
        num[7] += e1 * f3.y + e2 * g3.y + e3 * h3.y + e4 * k3.y;
        num[8] += e1 * f4.x + e2 * g4.x + e3 * h4.x + e4 * k4.x;
        num[9] += e1 * f4.y + e2 * g4.y + e3 * h4.y + e4 * k4.y;
    }
    for (; j < e0; ++j) {
        u64 r1 = rec[start + sIdx[j]];
        float e1;
        float2 f0, f1, f2, f3, f4;
        gath(xph, r1, e1, f0, f1, f2, f3, f4);
        den += e1;
        num[0] += e1 * f0.x; num[1] += e1 * f0.y;
        num[2] += e1 * f1.x; num[3] += e1 * f1.y;
        num[4] += e1 * f2.x; num[5] += e1 * f2.y;
        num[6] += e1 * f3.x; num[7] += e1 * f3.y;
        num[8] += e1 * f4.x; num[9] += e1 * f4.y;
    }
    int node = b * NPB + t;
    if (node >= NN) return;                  // no barriers after this point
    float l = a_s[node] + a_d[node] + ws_ro[OFF_LOOPAE];
    l = l > 0.f ? l : NEG_SLOPE * l;
    float exs = __expf(l);
    float inv = 1.0f / (den + exs);
    const unsigned* pn = (const unsigned*)(xph + (size_t)node * XPH);
    uint4 An = *(const uint4*)pn; unsigned Bn = pn[4];
    float xn[F_OUT];
    {
        float2 f0 = __half22float2(*(const __half2*)&An.x);
        float2 f1 = __half22float2(*(const __half2*)&An.y);
        float2 f2 = __half22float2(*(const __half2*)&An.z);
        float2 f3 = __half22float2(*(const __half2*)&An.w);
        float2 f4 = __half22float2(*(const __half2*)&Bn);
        xn[0]=f0.x; xn[1]=f0.y; xn[2]=f1.x; xn[3]=f1.y; xn[4]=f2.x;
        xn[5]=f2.y; xn[6]=f3.x; xn[7]=f3.y; xn[8]=f4.x; xn[9]=f4.y;
    }
    float o[F_OUT], y1[F_OUT], y2[F_OUT];
#pragma unroll
    for (int k = 0; k < F_OUT; ++k) {
        o[k] = (num[k] + exs * xn[k]) * inv + sb[k];
        out[(size_t)node * F_OUT + k] = fmaxf(o[k], 0.f);   // embeddings
    }
#pragma unroll
    for (int k = 0; k < F_OUT; ++k) {
        float a = sb1[k];
#pragma unroll
        for (int jj = 0; jj < F_OUT; ++jj) a += s1[k * F_OUT + jj] * o[jj];
        y1[k] = fmaxf(a, 0.f);
    }
#pragma unroll
    for (int k = 0; k < F_OUT; ++k) {
        float a = sb2[k];
#pragma unroll
        for (int jj = 0; jj < F_OUT; ++jj) a += s2[k * F_OUT + jj] * y1[jj];
        y2[k] = fmaxf(a, 0.f);
    }
#pragma unroll
    for (int k = 0; k < F_OUT; ++k) {
        float a = sb3[k];
#pragma unroll
        for (int jj = 0; jj < F_OUT; ++jj) a += s3[k * F_OUT + jj] * y2[jj];
        out[(size_t)NN * F_OUT + (size_t)node * F_OUT + k] = a;   // y
    }
}

extern "C" void kernel_launch(void* const* d_in, const int* in_sizes, int n_in,
                              void* d_out, int out_size, void* d_ws, size_t ws_size,
                              hipStream_t stream) {
    const float* h        = (const float*)d_in[0];
    const int*   ei       = (const int*)  d_in[1];
    const float* ew       = (const float*)d_in[2];
    const float* bn_w     = (const float*)d_in[3];
    const float* bn_b     = (const float*)d_in[4];
    const float* W        = (const float*)d_in[5];
    const float* att_src  = (const float*)d_in[6];
    const float* att_dst  = (const float*)d_in[7];
    const float* att_edge = (const float*)d_in[8];
    const float* W_edge   = (const float*)d_in[9];
    const float* bias     = (const float*)d_in[10];
    const float* fc1w     = (const float*)d_in[11];
    const float* fc1b     = (const float*)d_in[12];
    const float* fc2w     = (const float*)d_in[13];
    const float* fc2b     = (const float*)d_in[14];
    const float* fc3w     = (const float*)d_in[15];
    const float* fc3b     = (const float*)d_in[16];
    float* ws  = (float*)d_ws;
    int*   wsi = (int*)d_ws;
    float* out = (float*)d_out;
    __half* xph = (__half*)(ws + OFF_XP);

    k_hstats<<<HSB, 256, 0, stream>>>(h, ws + OFF_PART);
    k_ewsum <<<HSB, 256, 0, stream>>>(ew, ws + OFF_PEW);
    k_params<<<1, 64, 0, stream>>>(bn_w, bn_b, W_edge, att_edge,
                                   ws + OFF_PART, ws + OFF_PEW, ws);
    k_node  <<<(NN + 255) / 256, 256, 0, stream>>>(h, W, att_src, att_dst, ws,
                                                   xph, ws + OFF_AS, ws + OFF_AD);
    k_bcount<<<NBLK, SB, 0, stream>>>(ei, wsi + OFF_M);
    k_scan1 <<<G1, SCANB, 0, stream>>>(wsi + OFF_M, wsi + OFF_SCN, wsi + OFF_BS);
    k_scan2 <<<1, SCANB, 0, stream>>>(wsi + OFF_BS, wsi + OFF_SCN);
    k_scan3 <<<G1, SCANB, 0, stream>>>(wsi + OFF_SCN, wsi + OFF_BS);
    k_scatter<<<NBLK, SB, 0, stream>>>(ei, ew, ws, ws + OFF_AS, ws + OFF_AD,
                                       wsi + OFF_SCN, (u64*)(wsi + OFF_REC));
    k_creduce<<<NBUCK, RT, 0, stream>>>(ws, wsi + OFF_SCN, (const u64*)(wsi + OFF_REC),
                                        xph, ws + OFF_AS, ws + OFF_AD,
                                        bias, fc1w, fc1b, fc2w, fc2b, fc3w, fc3b, out);
}

// Round 9
// 466.548 us; speedup vs baseline: 1.8516x; 1.1404x over previous
//
#include <hip/hip_runtime.h>
#include <hip/hip_fp16.h>

#define NN 200000
#define NE 6400000
#define F_IN 20
#define F_OUT 10
#define XPH 16              // xp row stride in halves: 32B, 2 rows per cache line
#define NEG_SLOPE 0.2f
#define BN_EPS 1e-5f

#define NPB 512             // nodes per bucket = dst >> 9 (power of 2)
#define NBUCK 391           // ceil(NN/512)
#define CHUNK 4096          // edges per scatter block (LDS-sortable)
#define NBLK 1563           // ceil(NE/CHUNK)
#define SB 256              // scatter/bcount block size
#define NPT (CHUNK / SB)    // 16 records per thread
#define SZ (NBUCK * NBLK)   // 611133
#define SCANB 1024
#define G1 ((SZ + SCANB - 1) / SCANB)   // 597
#define HSB 240             // stats partial blocks
#define RT 512              // creduce threads (one per node in bucket)
#define MAXB 17664          // mean 16368 + 10 sigma; fits ushort

// ---- workspace float/int offsets ----
#define OFF_C      41
#define OFF_LOOPAE 42
#define OFF_SCALE  64
#define OFF_SHIFT  84
#define OFF_PART   128                      // HSB*40 partials
#define OFF_PEW    (OFF_PART + HSB * 40)
#define OFF_AS     (OFF_PEW + HSB)
#define OFF_AD     (OFF_AS + NN)
#define OFF_XP     (OFF_AD + NN)            // fp16 table: 8*NN floats worth, 32B-aligned
#define OFF_SCN    (OFF_XP + 8 * NN)        // SZ+1 ints (bucket-major scan)
#define OFF_BS     (OFF_SCN + SZ + 1)       // 1024 ints
#define OFF_SCT    (OFF_BS + 1024)          // SZ ints (chunk-major transpose)
#define OFF_M      (((OFF_SCT + SZ) + 1) & ~1)   // SZ ints; REC overlays (dead after scan)
#define OFF_REC    OFF_M                    // 2*NE ints (8B records)

typedef unsigned long long u64;

// ---------------- column stats of h: per-block partials ----------------
__global__ void k_hstats(const float* __restrict__ h, float* __restrict__ part) {
    float s[F_IN], q[F_IN];
#pragma unroll
    for (int f = 0; f < F_IN; ++f) { s[f] = 0.f; q[f] = 0.f; }
    for (int i = blockIdx.x * blockDim.x + threadIdx.x; i < NN;
         i += gridDim.x * blockDim.x) {
        const float4* row = (const float4*)(h + (size_t)i * F_IN);
#pragma unroll
        for (int v = 0; v < 5; ++v) {
            float4 x = row[v];
            int f = v * 4;
            s[f+0] += x.x; q[f+0] += x.x * x.x;
            s[f+1] += x.y; q[f+1] += x.y * x.y;
            s[f+2] += x.z; q[f+2] += x.z * x.z;
            s[f+3] += x.w; q[f+3] += x.w * x.w;
        }
    }
#pragma unroll
    for (int f = 0; f < F_IN; ++f)
        for (int o = 32; o > 0; o >>= 1) {
            s[f] += __shfl_down(s[f], o);
            q[f] += __shfl_down(q[f], o);
        }
    __shared__ float red[4][40];
    int t = threadIdx.x, wave = t >> 6, lane = t & 63;
    if (lane == 0) {
#pragma unroll
        for (int f = 0; f < F_IN; ++f) { red[wave][f] = s[f]; red[wave][F_IN + f] = q[f]; }
    }
    __syncthreads();
    if (t < 40) part[blockIdx.x * 40 + t] = red[0][t] + red[1][t] + red[2][t] + red[3][t];
}

// ---------------- sum of edge_weight: per-block partials ----------------
__global__ void k_ewsum(const float* __restrict__ ew, float* __restrict__ pew) {
    float s = 0.f;
    const float4* e4 = (const float4*)ew;
    const int n4 = NE / 4;
    for (int i = blockIdx.x * blockDim.x + threadIdx.x; i < n4;
         i += gridDim.x * blockDim.x) {
        float4 x = e4[i];
        s += x.x + x.y + x.z + x.w;
    }
    for (int o = 32; o > 0; o >>= 1) s += __shfl_down(s, o);
    __shared__ float red[4];
    int t = threadIdx.x;
    if ((t & 63) == 0) red[t >> 6] = s;
    __syncthreads();
    if (t == 0) pew[blockIdx.x] = red[0] + red[1] + red[2] + red[3];
}

// ---------------- finalize scalar params ----------------
__global__ void k_params(const float* __restrict__ bn_w, const float* __restrict__ bn_b,
                         const float* __restrict__ W_edge, const float* __restrict__ att_edge,
                         const float* __restrict__ part, const float* __restrict__ pew,
                         float* __restrict__ ws) {
    __shared__ float col[40];
    __shared__ float ews;
    int t = threadIdx.x;
    if (t < 40) {
        float s = 0.f;
#pragma unroll 8
        for (int b = 0; b < HSB; ++b) s += part[b * 40 + t];
        col[t] = s;
    }
    if (t == 40) {
        float s = 0.f;
#pragma unroll 8
        for (int b = 0; b < HSB; ++b) s += pew[b];
        ews = s;
    }
    __syncthreads();
    if (t < F_IN) {
        float mu  = col[t] / (float)NN;
        float var = col[F_IN + t] / (float)NN - mu * mu;
        float sc  = bn_w[t] * rsqrtf(var + BN_EPS);
        ws[OFF_SCALE + t] = sc;
        ws[OFF_SHIFT + t] = bn_b[t] - mu * sc;
    }
    if (t == 63) {
        float c = 0.f;
#pragma unroll
        for (int k = 0; k < F_OUT; ++k) c += W_edge[k] * att_edge[k];
        ws[OFF_C] = c;
        ws[OFF_LOOPAE] = c * (ews / (float)NE);
    }
}

// ---------------- per-node: BN + projection + attention; xp stored fp16 ----------------
__global__ void k_node(const float* __restrict__ h, const float* __restrict__ W,
                       const float* __restrict__ att_src, const float* __restrict__ att_dst,
                       const float* __restrict__ ws_ro, __half* __restrict__ xph,
                       float* __restrict__ a_s, float* __restrict__ a_d) {
    __shared__ float sW[F_OUT * F_IN], sAs[F_OUT], sAd[F_OUT], sSc[F_IN], sSh[F_IN];
    int t = threadIdx.x;
    if (t < F_OUT * F_IN) sW[t] = W[t];
    if (t < F_OUT) { sAs[t] = att_src[t]; sAd[t] = att_dst[t]; }
    if (t >= 224 && t < 224 + F_IN) {
        sSc[t - 224] = ws_ro[OFF_SCALE + (t - 224)];
        sSh[t - 224] = ws_ro[OFF_SHIFT + (t - 224)];
    }
    __syncthreads();
    int i = blockIdx.x * blockDim.x + t;
    if (i >= NN) return;
    float xn[F_IN];
    const float4* row = (const float4*)(h + (size_t)i * F_IN);
#pragma unroll
    for (int v = 0; v < 5; ++v) {
        float4 x = row[v];
        int f = v * 4;
        xn[f+0] = x.x * sSc[f+0] + sSh[f+0];
        xn[f+1] = x.y * sSc[f+1] + sSh[f+1];
        xn[f+2] = x.z * sSc[f+2] + sSh[f+2];
        xn[f+3] = x.w * sSc[f+3] + sSh[f+3];
    }
    float acc[F_OUT];
    float as = 0.f, ad = 0.f;
#pragma unroll
    for (int k = 0; k < F_OUT; ++k) {
        float a = 0.f;
#pragma unroll
        for (int f = 0; f < F_IN; ++f) a += sW[k * F_IN + f] * xn[f];
        acc[k] = a;
        as += a * sAs[k];
        ad += a * sAd[k];
    }
    __half2 h01 = __floats2half2_rn(acc[0], acc[1]);
    __half2 h23 = __floats2half2_rn(acc[2], acc[3]);
    __half2 h45 = __floats2half2_rn(acc[4], acc[5]);
    __half2 h67 = __floats2half2_rn(acc[6], acc[7]);
    __half2 h89 = __floats2half2_rn(acc[8], acc[9]);
    unsigned* dst = (unsigned*)(xph + (size_t)i * XPH);
    uint4 U;
    U.x = *(unsigned*)&h01; U.y = *(unsigned*)&h23;
    U.z = *(unsigned*)&h45; U.w = *(unsigned*)&h67;
    *(uint4*)dst = U;
    dst[4] = *(unsigned*)&h89;
    a_s[i] = as;
    a_d[i] = ad;
}

// ---------------- pass A: per-(bucket, chunk) edge counts ----------------
__global__ void k_bcount(const int* __restrict__ ei, int* __restrict__ M) {
    __shared__ int hist[NBUCK];
    int t = threadIdx.x, blk = blockIdx.x;
    for (int i = t; i < NBUCK; i += SB) hist[i] = 0;
    __syncthreads();
    int base = blk * CHUNK;
    int lim = NE - base; if (lim > CHUNK) lim = CHUNK;
    for (int j = t; j < lim; j += SB) {
        int dst = ei[NE + base + j];
        atomicAdd(&hist[dst >> 9], 1);
    }
    __syncthreads();
    for (int i = t; i < NBUCK; i += SB) M[i * NBLK + blk] = hist[i];
}

// ---------------- scan (bucket-major) ----------------
__global__ void k_scan1(const int* __restrict__ M, int* __restrict__ SCN,
                        int* __restrict__ BS) {
    __shared__ int tmp[SCANB];
    int t = threadIdx.x, g = blockIdx.x;
    int idx = g * SCANB + t;
    int v = (idx < SZ) ? M[idx] : 0;
    tmp[t] = v;
    __syncthreads();
    for (int off = 1; off < SCANB; off <<= 1) {
        int x = (t >= off) ? tmp[t - off] : 0;
        __syncthreads();
        tmp[t] += x;
        __syncthreads();
    }
    if (idx < SZ) SCN[idx] = tmp[t] - v;
    if (t == SCANB - 1) BS[g] = tmp[t];
}

__global__ void k_scan2(int* __restrict__ BS, int* __restrict__ SCN) {
    __shared__ int tmp[SCANB];
    int t = threadIdx.x;
    int v = (t < G1) ? BS[t] : 0;
    tmp[t] = v;
    __syncthreads();
    for (int off = 1; off < SCANB; off <<= 1) {
        int x = (t >= off) ? tmp[t - off] : 0;
        __syncthreads();
        tmp[t] += x;
        __syncthreads();
    }
    if (t < G1) BS[t] = tmp[t] - v;
    if (t == 0) SCN[SZ] = NE;
}

// finalize + write chunk-major transpose (coalesced base loads for k_scatter)
__global__ void k_scan3(int* __restrict__ SCN, const int* __restrict__ BS,
                        int* __restrict__ SCT) {
    int idx = blockIdx.x * SCANB + threadIdx.x;
    if (idx < SZ) {
        int v = SCN[idx] + BS[blockIdx.x];
        SCN[idx] = v;
        int b   = idx / NBLK;
        int blk = idx - b * NBLK;
        SCT[blk * NBUCK + b] = v;            // scattered 4B write, tiny buffer
    }
}

// ---------------- pass B: LDS counting sort per chunk + coalesced run copy ----------------
// r8 lesson: time-separated 8B scatter stores never merge in L2 (WRITE 190MB for
// a 51MB array). Sorting the chunk in LDS makes run stores lane-contiguous, so
// they coalesce within a single wave instruction.
__global__ void __launch_bounds__(SB) k_scatter(
        const int* __restrict__ ei, const float* __restrict__ ew,
        const float* __restrict__ ws_ro,
        const float* __restrict__ a_s, const float* __restrict__ a_d,
        const int* __restrict__ SCT, u64* __restrict__ rec) {
    __shared__ u64 sBuf[CHUNK];              // 32 KB sorted records
    __shared__ int sScan[512];               // hist -> exclusive offsets (zero-padded)
    __shared__ int sCur[NBUCK];
    __shared__ int sBase[NBUCK];
    int t = threadIdx.x, blk = blockIdx.x;
    sScan[t] = 0; sScan[t + SB] = 0;
    for (int i = t; i < NBUCK; i += SB) sBase[i] = SCT[blk * NBUCK + i];
    __syncthreads();
    int base = blk * CHUNK;
    int lim = NE - base; if (lim > CHUNK) lim = CHUNK;
    float c = ws_ro[OFF_C];
    u64 r[NPT]; int bk[NPT];
#pragma unroll
    for (int k = 0; k < NPT; ++k) {
        int j = t + k * SB;
        bk[k] = -1;
        if (j < lim) {
            int e = base + j;
            int src = __builtin_nontemporal_load(ei + e);
            int dst = ei[NE + e];
            float w  = __builtin_nontemporal_load(ew + e);
            float logit = a_s[src] + a_d[dst] + c * w;
            logit = logit > 0.f ? logit : NEG_SLOPE * logit;
            float ex = __expf(logit);
            int b = dst >> 9;
            bk[k] = b;
            r[k] = ((u64)__float_as_uint(ex) << 32) |
                   (u64)(((unsigned)src << 9) | (unsigned)(dst & (NPB - 1)));
            atomicAdd(&sScan[b], 1);
        }
    }
    __syncthreads();
    // Blelloch exclusive scan over 512 bins with 256 threads
    for (int d = 1; d < 512; d <<= 1) {
        int idx = (t + 1) * (d << 1) - 1;
        if (idx < 512) sScan[idx] += sScan[idx - d];
        __syncthreads();
    }
    if (t == 0) sScan[511] = 0;
    __syncthreads();
    for (int d = 256; d >= 1; d >>= 1) {
        int idx = (t + 1) * (d << 1) - 1;
        if (idx < 512) {
            int x = sScan[idx - d];
            sScan[idx - d] = sScan[idx];
            sScan[idx] += x;
        }
        __syncthreads();
    }
    for (int i = t; i < NBUCK; i += SB) sCur[i] = sScan[i];
    __syncthreads();
    // place records into LDS in bucket-sorted order
#pragma unroll
    for (int k = 0; k < NPT; ++k) {
        if (bk[k] >= 0) {
            int p = atomicAdd(&sCur[bk[k]], 1);
            sBuf[p] = r[k];
        }
    }
    __syncthreads();
    // wave-cooperative run copy: lane-contiguous stores coalesce
    int wave = t >> 6, lane = t & 63;
    for (int b = wave; b < NBUCK; b += SB / 64) {
        int st = sScan[b];
        int len = sScan[b + 1] - st;         // buckets >= NBUCK are zero-count pads
        int gb = sBase[b];
        for (int k2 = lane; k2 < len; k2 += 64)
            rec[gb + k2] = sBuf[st + k2];
    }
}

// ---------------- pass C: in-bucket counting sort + register accumulate + MLP ----------------
__device__ __forceinline__ void gath(const __half* __restrict__ xph, u64 r,
                                     float& ex, float2& f0, float2& f1,
                                     float2& f2, float2& f3, float2& f4) {
    ex = __uint_as_float((unsigned)(r >> 32));
    const unsigned* p = (const unsigned*)(xph + (size_t)((unsigned)r >> 9) * XPH);
    uint4 A = *(const uint4*)p; unsigned B = p[4];
    f0 = __half22float2(*(const __half2*)&A.x);
    f1 = __half22float2(*(const __half2*)&A.y);
    f2 = __half22float2(*(const __half2*)&A.z);
    f3 = __half22float2(*(const __half2*)&A.w);
    f4 = __half22float2(*(const __half2*)&B);
}

__global__ void __launch_bounds__(RT, 8) k_creduce(
        const float* __restrict__ ws_ro, const int* __restrict__ SCN,
        const u64* __restrict__ rec, const __half* __restrict__ xph,
        const float* __restrict__ a_s, const float* __restrict__ a_d,
        const float* __restrict__ bias,
        const float* __restrict__ fc1w, const float* __restrict__ fc1b,
        const float* __restrict__ fc2w, const float* __restrict__ fc2b,
        const float* __restrict__ fc3w, const float* __restrict__ fc3b,
        float* __restrict__ out) {
    __shared__ unsigned short sIdx[MAXB];
    __shared__ int sHist[RT];                // hist -> scan (in place) -> cursor
    __shared__ float s1[100], s2[100], s3[100], sb[F_OUT], sb1[F_OUT], sb2[F_OUT], sb3[F_OUT];
    int t = threadIdx.x, b = blockIdx.x;
    sHist[t] = 0;
    if (t < 100) { s1[t] = fc1w[t]; s2[t] = fc2w[t]; s3[t] = fc3w[t]; }
    if (t >= 128 && t < 128 + F_OUT) {
        int k = t - 128;
        sb[k] = bias[k]; sb1[k] = fc1b[k]; sb2[k] = fc2b[k]; sb3[k] = fc3b[k];
    }
    __syncthreads();
    int start = SCN[b * NBLK];
    int cnt = SCN[(b + 1) * NBLK] - start;
    if (cnt > MAXB) cnt = MAXB;              // 10-sigma safety clamp
    const unsigned* recx = (const unsigned*)rec;
    for (int i = t; i < cnt; i += RT)
        atomicAdd(&sHist[recx[2 * (size_t)(start + i)] & (NPB - 1u)], 1);
    __syncthreads();
    int deg = sHist[t];
    for (int off = 1; off < RT; off <<= 1) {
        int x = (t >= off) ? sHist[t - off] : 0;
        __syncthreads();
        sHist[t] += x;
        __syncthreads();
    }
    int myStart = sHist[t] - deg;
    __syncthreads();
    sHist[t] = myStart;                      // reuse as cursor
    __syncthreads();
    for (int i = t; i < cnt; i += RT) {
        unsigned lo = recx[2 * (size_t)(start + i)];
        int p = atomicAdd(&sHist[lo & (NPB - 1u)], 1);
        if (p < MAXB) sIdx[p] = (unsigned short)i;
    }
    __syncthreads();
    float den = 0.f;
    float num[F_OUT];
#pragma unroll
    for (int k = 0; k < F_OUT; ++k) num[k] = 0.f;
    int e0 = myStart + deg;
    int j = myStart;
    for (; j + 3 < e0; j += 4) {
        u64 r1 = rec[start + sIdx[j]];
        u64 r2 = rec[start + sIdx[j + 1]];
        u64 r3 = rec[start + sIdx[j + 2]];
        u64 r4 = rec[start + sIdx[j + 3]];
        float e1, e2, e3, e4;
        float2 f0, f1, f2, f3, f4, g0, g1, g2, g3, g4;
        float2 h0, h1, h2, h3, h4, k0, k1, k2, k3, k4;
        gath(xph, r1, e1, f0, f1, f2, f3, f4);
        gath(xph, r2, e2, g0, g1, g2, g3, g4);
        gath(xph, r3, e3, h0, h1, h2, h3, h4);
        gath(xph, r4, e4, k0, k1, k2, k3, k4);
        den += (e1 + e2) + (e3 + e4);
        num[0] += e1 * f0.x + e2 * g0.x + e3 * h0.x + e4 * k0.x;
        num[1] += e1 * f0.y + e2 * g0.y + e3 * h0.y + e4 * k0.y;
        num[2] += e1 * f1.x + e2 * g1.x + e3 * h1.x + e4 * k1.x;
        num[3] += e1 * f1.y + e2 * g1.y + e3 * h1.y + e4 * k1.y;
        num[4] += e1 * f2.x + e2 * g2.x + e3 * h2.x + e4 * k2.x;
        num[5] += e1 * f2.y + e2 * g2.y + e3 * h2.y + e4 * k2.y;
        num[6] += e1 * f3.x + e2 * g3.x + e3 * h3.x + e4 * k3.x;
        num[7] += e1 * f3.y + e2 * g3.y + e3 * h3.y + e4 * k3.y;
        num[8] += e1 * f4.x + e2 * g4.x + e3 * h4.x + e4 * k4.x;
        num[9] += e1 * f4.y + e2 * g4.y + e3 * h4.y + e4 * k4.y;
    }
    for (; j < e0; ++j) {
        u64 r1 = rec[start + sIdx[j]];
        float e1;
        float2 f0, f1, f2, f3, f4;
        gath(xph, r1, e1, f0, f1, f2, f3, f4);
        den += e1;
        num[0] += e1 * f0.x; num[1] += e1 * f0.y;
        num[2] += e1 * f1.x; num[3] += e1 * f1.y;
        num[4] += e1 * f2.x; num[5] += e1 * f2.y;
        num[6] += e1 * f3.x; num[7] += e1 * f3.y;
        num[8] += e1 * f4.x; num[9] += e1 * f4.y;
    }
    int node = b * NPB + t;
    if (node >= NN) return;                  // no barriers after this point
    float l = a_s[node] + a_d[node] + ws_ro[OFF_LOOPAE];
    l = l > 0.f ? l : NEG_SLOPE * l;
    float exs = __expf(l);
    float inv = 1.0f / (den + exs);
    const unsigned* pn = (const unsigned*)(xph + (size_t)node * XPH);
    uint4 An = *(const uint4*)pn; unsigned Bn = pn[4];
    float xn[F_OUT];
    {
        float2 f0 = __half22float2(*(const __half2*)&An.x);
        float2 f1 = __half22float2(*(const __half2*)&An.y);
        float2 f2 = __half22float2(*(const __half2*)&An.z);
        float2 f3 = __half22float2(*(const __half2*)&An.w);
        float2 f4 = __half22float2(*(const __half2*)&Bn);
        xn[0]=f0.x; xn[1]=f0.y; xn[2]=f1.x; xn[3]=f1.y; xn[4]=f2.x;
        xn[5]=f2.y; xn[6]=f3.x; xn[7]=f3.y; xn[8]=f4.x; xn[9]=f4.y;
    }
    float o[F_OUT], y1[F_OUT], y2[F_OUT];
#pragma unroll
    for (int k = 0; k < F_OUT; ++k) {
        o[k] = (num[k] + exs * xn[k]) * inv + sb[k];
        out[(size_t)node * F_OUT + k] = fmaxf(o[k], 0.f);   // embeddings
    }
#pragma unroll
    for (int k = 0; k < F_OUT; ++k) {
        float a = sb1[k];
#pragma unroll
        for (int jj = 0; jj < F_OUT; ++jj) a += s1[k * F_OUT + jj] * o[jj];
        y1[k] = fmaxf(a, 0.f);
    }
#pragma unroll
    for (int k = 0; k < F_OUT; ++k) {
        float a = sb2[k];
#pragma unroll
        for (int jj = 0; jj < F_OUT; ++jj) a += s2[k * F_OUT + jj] * y1[jj];
        y2[k] = fmaxf(a, 0.f);
    }
#pragma unroll
    for (int k = 0; k < F_OUT; ++k) {
        float a = sb3[k];
#pragma unroll
        for (int jj = 0; jj < F_OUT; ++jj) a += s3[k * F_OUT + jj] * y2[jj];
        out[(size_t)NN * F_OUT + (size_t)node * F_OUT + k] = a;   // y
    }
}

extern "C" void kernel_launch(void* const* d_in, const int* in_sizes, int n_in,
                              void* d_out, int out_size, void* d_ws, size_t ws_size,
                              hipStream_t stream) {
    const float* h        = (const float*)d_in[0];
    const int*   ei       = (const int*)  d_in[1];
    const float* ew       = (const float*)d_in[2];
    const float* bn_w     = (const float*)d_in[3];
    const float* bn_b     = (const float*)d_in[4];
    const float* W        = (const float*)d_in[5];
    const float* att_src  = (const float*)d_in[6];
    const float* att_dst  = (const float*)d_in[7];
    const float* att_edge = (const float*)d_in[8];
    const float* W_edge   = (const float*)d_in[9];
    const float* bias     = (const float*)d_in[10];
    const float* fc1w     = (const float*)d_in[11];
    const float* fc1b     = (const float*)d_in[12];
    const float* fc2w     = (const float*)d_in[13];
    const float* fc2b     = (const float*)d_in[14];
    const float* fc3w     = (const float*)d_in[15];
    const float* fc3b     = (const float*)d_in[16];
    float* ws  = (float*)d_ws;
    int*   wsi = (int*)d_ws;
    float* out = (float*)d_out;
    __half* xph = (__half*)(ws + OFF_XP);

    k_hstats<<<HSB, 256, 0, stream>>>(h, ws + OFF_PART);
    k_ewsum <<<HSB, 256, 0, stream>>>(ew, ws + OFF_PEW);
    k_params<<<1, 64, 0, stream>>>(bn_w, bn_b, W_edge, att_edge,
                                   ws + OFF_PART, ws + OFF_PEW, ws);
    k_node  <<<(NN + 255) / 256, 256, 0, stream>>>(h, W, att_src, att_dst, ws,
                                                   xph, ws + OFF_AS, ws + OFF_AD);
    k_bcount<<<NBLK, SB, 0, stream>>>(ei, wsi + OFF_M);
    k_scan1 <<<G1, SCANB, 0, stream>>>(wsi + OFF_M, wsi + OFF_SCN, wsi + OFF_BS);
    k_scan2 <<<1, SCANB, 0, stream>>>(wsi + OFF_BS, wsi + OFF_SCN);
    k_scan3 <<<G1, SCANB, 0, stream>>>(wsi + OFF_SCN, wsi + OFF_BS, wsi + OFF_SCT);
    k_scatter<<<NBLK, SB, 0, stream>>>(ei, ew, ws, ws + OFF_AS, ws + OFF_AD,
                                       wsi + OFF_SCT, (u64*)(wsi + OFF_REC));
    k_creduce<<<NBUCK, RT, 0, stream>>>(ws, wsi + OFF_SCN, (const u64*)(wsi + OFF_REC),
                                        xph, ws + OFF_AS, ws + OFF_AD,
                                        bias, fc1w, fc1b, fc2w, fc2b, fc3w, fc3b, out);
}